// Round 1
// baseline (139.246 us; speedup 1.0000x reference)
//
#include <hip/hip_runtime.h>
#include <math.h>

#ifndef M_PI
#define M_PI 3.14159265358979323846
#endif

#define LUT_N 4096

// nearest-entry LUT cos, replicating jnp round-half-even + float mod semantics
__device__ __forceinline__ float lut_cos(float theta) {
    const float IDX_SCALE = (float)((double)LUT_N / (2.0 * M_PI)); // fl(4096/2pi)
    const float STEP = (float)((2.0 * M_PI) / (double)LUT_N);      // fl(2pi/4096)
    float x = theta * IDX_SCALE;
    int i = (int)rintf(x);     // round-half-even, matches jnp.round/np.round
    i &= (LUT_N - 1);          // == Python mod for pow2 in two's complement
    return cosf((float)i * STEP);
}

__global__ void qgen_kernel(const float* __restrict__ cur_r,
                            const float* __restrict__ cur_i,
                            const float* __restrict__ w_q,
                            const float* __restrict__ b_q,
                            const float* __restrict__ t_ptr,
                            float* __restrict__ q_out,
                            int B, int D) {
    int idx = blockIdx.x * blockDim.x + threadIdx.x;
    int twoD = 2 * D;
    if (idx >= B * twoD) return;
    int b = idx / twoD;
    int c = idx - b * twoD;
    int col = (c < D) ? c : c - D;
    const float* src = (c < D) ? cur_r : cur_i;
    float v = src[(size_t)b * D + col];
    float t_phi = t_ptr[0] * 1.61803398874989484820f;  // f32(PHI), f32 multiply
    float wl = 1.0f + fabsf(w_q[col]);
    float theta = v / wl + b_q[col] + t_phi;           // same op order as ref
    q_out[idx] = lut_cos(theta);
}

// One block = (batch b, split s): online softmax over rows [s*rows, (s+1)*rows)
// Requires 2D == 4096 (thread t owns float4 lanes t+256j, j=0..3).
__global__ __launch_bounds__(256) void flash_kernel(
    const float* __restrict__ hist_r,
    const float* __restrict__ hist_i,
    const float* __restrict__ q_ws,
    float* __restrict__ r_ws,
    float* __restrict__ ml_ws,
    int H, int D, int S) {
    const int t = threadIdx.x;
    const int b = blockIdx.x / S;
    const int s = blockIdx.x - b * S;
    const int rows = H / S;
    const int h0 = s * rows;
    const int Dv = D >> 2;  // float4 per half-row (512)

    const float4* qv4 = (const float4*)q_ws + (size_t)b * (D >> 1);
    float4 qv[4], rv[4];
#pragma unroll
    for (int j = 0; j < 4; ++j) {
        qv[j] = qv4[t + 256 * j];
        rv[j] = make_float4(0.f, 0.f, 0.f, 0.f);
    }
    const float4* hr4 = (const float4*)hist_r + (size_t)b * H * Dv;
    const float4* hi4 = (const float4*)hist_i + (size_t)b * H * Dv;

    float m = -INFINITY, l = 0.0f;
    const float inv_scale = 1.0f / sqrtf(2.0f * (float)D);  // 1/64 exact
    __shared__ float red[4];

    for (int hh = 0; hh < rows; ++hh) {
        const size_t ro = (size_t)(h0 + hh) * Dv;
        float4 kv[4];
        kv[0] = hr4[ro + t];
        kv[1] = hr4[ro + t + 256];
        kv[2] = hi4[ro + t];
        kv[3] = hi4[ro + t + 256];
        float p = 0.f;
#pragma unroll
        for (int j = 0; j < 4; ++j)
            p += qv[j].x * kv[j].x + qv[j].y * kv[j].y +
                 qv[j].z * kv[j].z + qv[j].w * kv[j].w;
#pragma unroll
        for (int off = 32; off > 0; off >>= 1) p += __shfl_down(p, off);
        if ((t & 63) == 0) red[t >> 6] = p;
        __syncthreads();
        float sc = (red[0] + red[1] + red[2] + red[3]) * inv_scale;
        __syncthreads();
        float m_new = fmaxf(m, sc);
        float corr = expf(m - m_new);   // first iter: expf(-inf)=0
        float w = expf(sc - m_new);
        l = fmaf(l, corr, w);
#pragma unroll
        for (int j = 0; j < 4; ++j) {
            rv[j].x = fmaf(rv[j].x, corr, w * kv[j].x);
            rv[j].y = fmaf(rv[j].y, corr, w * kv[j].y);
            rv[j].z = fmaf(rv[j].z, corr, w * kv[j].z);
            rv[j].w = fmaf(rv[j].w, corr, w * kv[j].w);
        }
        m = m_new;
    }
    float4* rout = (float4*)r_ws + (size_t)(b * S + s) * (D >> 1);
#pragma unroll
    for (int j = 0; j < 4; ++j) rout[t + 256 * j] = rv[j];
    if (t == 0) {
        ml_ws[(size_t)(b * S + s) * 2] = m;
        ml_ws[(size_t)(b * S + s) * 2 + 1] = l;
    }
}

// grid = B * (2D/256) blocks; each thread owns one output column.
__global__ void combine_kernel(const float* __restrict__ r_ws,
                               const float* __restrict__ ml_ws,
                               const float* __restrict__ ema,
                               const float* __restrict__ alpha_ptr,
                               float* __restrict__ out,
                               int D, int S) {
    const int twoD = 2 * D;
    const int nc = twoD / 256;
    const int b = blockIdx.x / nc;
    const int cb = blockIdx.x - b * nc;
    const int c = cb * 256 + threadIdx.x;

    const float* ml = ml_ws + (size_t)b * S * 2;
    float M = -INFINITY;
    for (int s = 0; s < S; ++s) M = fmaxf(M, ml[2 * s]);
    float L = 0.f;
    for (int s = 0; s < S; ++s) L += ml[2 * s + 1] * expf(ml[2 * s] - M);

    float acc = 0.f;
    const float* rb = r_ws + (size_t)b * S * twoD + c;
    for (int s = 0; s < S; ++s)
        acc = fmaf(expf(ml[2 * s] - M), rb[(size_t)s * twoD], acc);

    float a = 1.0f / (1.0f + expf(-alpha_ptr[0]));  // sigmoid(alpha)
    float retrieved = acc / L;
    size_t o = (size_t)b * twoD + c;
    out[o] = a * retrieved + (1.0f - a) * ema[o];
}

extern "C" void kernel_launch(void* const* d_in, const int* in_sizes, int n_in,
                              void* d_out, int out_size, void* d_ws, size_t ws_size,
                              hipStream_t stream) {
    const float* cur_r  = (const float*)d_in[0];
    const float* cur_i  = (const float*)d_in[1];
    const float* hist_r = (const float*)d_in[2];
    const float* hist_i = (const float*)d_in[3];
    const float* ema    = (const float*)d_in[4];
    const float* w_q    = (const float*)d_in[5];
    const float* b_q    = (const float*)d_in[6];
    const float* alpha  = (const float*)d_in[7];
    const float* t      = (const float*)d_in[8];

    const int D = in_sizes[5];                 // 2048
    const int B = in_sizes[0] / D;             // 16
    const int H = in_sizes[2] / (B * D);       // 2048
    const int twoD = 2 * D;

    float* q_ws = (float*)d_ws;
    size_t q_elems = (size_t)B * twoD;

    int S = 64;  // splits per batch: 1024 blocks, 32 rows each
    while (S > 1) {
        size_t need = (q_elems + (size_t)B * S * twoD + (size_t)B * S * 2) * sizeof(float);
        if (need <= ws_size) break;
        S >>= 1;
    }
    float* r_ws = q_ws + q_elems;
    float* ml_ws = r_ws + (size_t)B * S * twoD;

    int qblocks = (B * twoD + 255) / 256;
    qgen_kernel<<<qblocks, 256, 0, stream>>>(cur_r, cur_i, w_q, b_q, t, q_ws, B, D);
    flash_kernel<<<B * S, 256, 0, stream>>>(hist_r, hist_i, q_ws, r_ws, ml_ws, H, D, S);
    combine_kernel<<<B * (twoD / 256), 256, 0, stream>>>(r_ws, ml_ws, ema, alpha,
                                                         (float*)d_out, D, S);
}

// Round 2
// 124.109 us; speedup vs baseline: 1.1220x; 1.1220x over previous
//
#include <hip/hip_runtime.h>
#include <math.h>

#ifndef M_PI
#define M_PI 3.14159265358979323846
#endif

#define LUT_N 4096
#define RBATCH 4

// nearest-entry LUT cos, replicating jnp round-half-even + float mod semantics
__device__ __forceinline__ float lut_cos(float theta) {
    const float IDX_SCALE = (float)((double)LUT_N / (2.0 * M_PI)); // fl(4096/2pi)
    const float STEP = (float)((2.0 * M_PI) / (double)LUT_N);      // fl(2pi/4096)
    float x = theta * IDX_SCALE;
    int i = (int)rintf(x);     // round-half-even, matches jnp.round/np.round
    i &= (LUT_N - 1);          // == Python mod for pow2 in two's complement
    return cosf((float)i * STEP);
}

__global__ void qgen_kernel(const float* __restrict__ cur_r,
                            const float* __restrict__ cur_i,
                            const float* __restrict__ w_q,
                            const float* __restrict__ b_q,
                            const float* __restrict__ t_ptr,
                            float* __restrict__ q_out,
                            int B, int D) {
    int idx = blockIdx.x * blockDim.x + threadIdx.x;
    int twoD = 2 * D;
    if (idx >= B * twoD) return;
    int b = idx / twoD;
    int c = idx - b * twoD;
    int col = (c < D) ? c : c - D;
    const float* src = (c < D) ? cur_r : cur_i;
    float v = src[(size_t)b * D + col];
    float t_phi = t_ptr[0] * 1.61803398874989484820f;  // f32(PHI), f32 multiply
    float wl = 1.0f + fabsf(w_q[col]);
    float theta = v / wl + b_q[col] + t_phi;           // same op order as ref
    q_out[idx] = lut_cos(theta);
}

// Block = 1024 threads; thread t owns float4 column t of the 4096-wide key row
// (t<512 -> history_real half, t>=512 -> history_imag half).
// Each block handles split s of batch b: rows [s*rows, (s+1)*rows).
// Rows are processed in batches of RBATCH with ONE barrier per batch
// (double-buffered LDS partials) to break the per-row serial chain.
// Requires 2D == 4096.
__global__ __launch_bounds__(1024, 8) void flash_kernel(
    const float* __restrict__ hist_r,
    const float* __restrict__ hist_i,
    const float* __restrict__ q_ws,
    float* __restrict__ r_ws,
    float* __restrict__ ml_ws,
    int H, int S) {
    const int t = threadIdx.x;
    const int b = blockIdx.x / S;
    const int s = blockIdx.x - b * S;
    const int rows = H / S;
    const int h0 = s * rows;

    const int half = t >> 9;        // 0: real half, 1: imag half
    const int cc = t & 511;         // float4 index within the half-row (512 per row)
    const int wave = t >> 6, lane = t & 63;

    const float4* base = (const float4*)(half ? hist_i : hist_r)
                         + ((size_t)b * H + h0) * 512 + cc;
    float4 qv = ((const float4*)q_ws)[(size_t)b * 1024 + t];
    float4 rv = make_float4(0.f, 0.f, 0.f, 0.f);
    float m = -INFINITY, l = 0.0f;
    const float inv_scale = 1.0f / 64.0f;  // 1/sqrt(2*2048), exact

    __shared__ float part[2][RBATCH][16];  // [parity][row-in-batch][wave]

    const int nb = rows / RBATCH;
    for (int kb = 0; kb < nb; ++kb) {
        const float4* rp = base + (size_t)(kb * RBATCH) * 512;
        float4 kv[RBATCH];
#pragma unroll
        for (int i = 0; i < RBATCH; ++i) kv[i] = rp[(size_t)i * 512];

#pragma unroll
        for (int i = 0; i < RBATCH; ++i) {
            float p = qv.x * kv[i].x + qv.y * kv[i].y +
                      qv.z * kv[i].z + qv.w * kv[i].w;
#pragma unroll
            for (int off = 32; off > 0; off >>= 1) p += __shfl_down(p, off);
            if (lane == 0) part[kb & 1][i][wave] = p;
        }
        __syncthreads();  // one barrier per RBATCH rows; parity buffer avoids WAR

        const float4* pp = (const float4*)part[kb & 1];
#pragma unroll
        for (int i = 0; i < RBATCH; ++i) {
            float4 a0 = pp[4 * i + 0], a1 = pp[4 * i + 1];
            float4 a2 = pp[4 * i + 2], a3 = pp[4 * i + 3];
            float sc = ((a0.x + a0.y) + (a0.z + a0.w)) +
                       ((a1.x + a1.y) + (a1.z + a1.w)) +
                       ((a2.x + a2.y) + (a2.z + a2.w)) +
                       ((a3.x + a3.y) + (a3.z + a3.w));
            sc *= inv_scale;
            float m_new = fmaxf(m, sc);
            float corr = expf(m - m_new);   // first row: expf(-inf)=0
            float w = expf(sc - m_new);
            l = fmaf(l, corr, w);
            rv.x = fmaf(rv.x, corr, w * kv[i].x);
            rv.y = fmaf(rv.y, corr, w * kv[i].y);
            rv.z = fmaf(rv.z, corr, w * kv[i].z);
            rv.w = fmaf(rv.w, corr, w * kv[i].w);
            m = m_new;
        }
    }

    ((float4*)r_ws)[(size_t)(b * S + s) * 1024 + t] = rv;
    if (t == 0) {
        ml_ws[(size_t)(b * S + s) * 2] = m;
        ml_ws[(size_t)(b * S + s) * 2 + 1] = l;
    }
}

// grid = B * (2D/256) blocks; each thread owns one output column.
__global__ void combine_kernel(const float* __restrict__ r_ws,
                               const float* __restrict__ ml_ws,
                               const float* __restrict__ ema,
                               const float* __restrict__ alpha_ptr,
                               float* __restrict__ out,
                               int D, int S) {
    const int twoD = 2 * D;
    const int nc = twoD / 256;
    const int b = blockIdx.x / nc;
    const int cb = blockIdx.x - b * nc;
    const int c = cb * 256 + threadIdx.x;

    const float* ml = ml_ws + (size_t)b * S * 2;
    float M = -INFINITY;
    for (int s = 0; s < S; ++s) M = fmaxf(M, ml[2 * s]);
    float L = 0.f;
    for (int s = 0; s < S; ++s) L += ml[2 * s + 1] * expf(ml[2 * s] - M);

    float acc = 0.f;
    const float* rb = r_ws + (size_t)b * S * twoD + c;
    for (int s = 0; s < S; ++s)
        acc = fmaf(expf(ml[2 * s] - M), rb[(size_t)s * twoD], acc);

    float a = 1.0f / (1.0f + expf(-alpha_ptr[0]));  // sigmoid(alpha)
    float retrieved = acc / L;
    size_t o = (size_t)b * twoD + c;
    out[o] = a * retrieved + (1.0f - a) * ema[o];
}

extern "C" void kernel_launch(void* const* d_in, const int* in_sizes, int n_in,
                              void* d_out, int out_size, void* d_ws, size_t ws_size,
                              hipStream_t stream) {
    const float* cur_r  = (const float*)d_in[0];
    const float* cur_i  = (const float*)d_in[1];
    const float* hist_r = (const float*)d_in[2];
    const float* hist_i = (const float*)d_in[3];
    const float* ema    = (const float*)d_in[4];
    const float* w_q    = (const float*)d_in[5];
    const float* b_q    = (const float*)d_in[6];
    const float* alpha  = (const float*)d_in[7];
    const float* t      = (const float*)d_in[8];

    const int D = in_sizes[5];                 // 2048
    const int B = in_sizes[0] / D;             // 16
    const int H = in_sizes[2] / (B * D);       // 2048
    const int twoD = 2 * D;

    float* q_ws = (float*)d_ws;
    size_t q_elems = (size_t)B * twoD;

    int S = 32;  // 512 blocks of 1024 threads = 2 blocks/CU in one round
    while (S > 1) {
        size_t need = (q_elems + (size_t)B * S * twoD + (size_t)B * S * 2) * sizeof(float);
        if (need <= ws_size) break;
        S >>= 1;
    }
    float* r_ws = q_ws + q_elems;
    float* ml_ws = r_ws + (size_t)B * S * twoD;

    int qblocks = (B * twoD + 255) / 256;
    qgen_kernel<<<qblocks, 256, 0, stream>>>(cur_r, cur_i, w_q, b_q, t, q_ws, B, D);
    flash_kernel<<<B * S, 1024, 0, stream>>>(hist_r, hist_i, q_ws, r_ws, ml_ws, H, S);
    combine_kernel<<<B * (twoD / 256), 256, 0, stream>>>(r_ws, ml_ws, ema, alpha,
                                                         (float*)d_out, D, S);
}